// Round 3
// baseline (189.039 us; speedup 1.0000x reference)
//
#include <hip/hip_runtime.h>
#include <hip/hip_bf16.h>

typedef __attribute__((ext_vector_type(8))) short bf16x8;
typedef __attribute__((ext_vector_type(4))) float f32x4;

__device__ __forceinline__ unsigned short f2bf(float f) {
    unsigned int u = __builtin_bit_cast(unsigned int, f);
    u += 0x7fffu + ((u >> 16) & 1u);   // round-to-nearest-even
    return (unsigned short)(u >> 16);
}

// Swizzled byte offset inside a [128 rows][256 B] LDS tile (16B-unit XOR).
__device__ __forceinline__ int swz(int r, int k /*bf16 col*/) {
    int unit = k >> 3;
    return r * 256 + (((unit ^ (r & 15)) << 4) | ((k & 7) << 1));
}

__global__ __launch_bounds__(256, 2)
void gemm_persist(const float* __restrict__ A,  // (32, 2048, 128)
                  const float* __restrict__ B,  // (32, 128, 2048)
                  float* __restrict__ C) {      // (32, 2048, 2048)
    // LDS: only the transposed B tile (128n x 128k bf16, swizzled) = 32 KB,
    // staged ONCE per block; the mt-loop is barrier-free.
    __shared__ __align__(16) unsigned char lds[32768];

    // XCD-chunked mapping: consecutive bids round-robin XCDs, so give XCD x
    // the bh-panels [x*4, x*4+4) -> its L2 holds 4 MB of A instead of 32 MB.
    const int bid = blockIdx.x;            // 0..511
    const int c   = bid >> 3;              // 0..63
    const int bh  = (bid & 7) * 4 + (c >> 4);  // 0..31
    const int nt  = c & 15;                // 0..15

    const float* Bg  = B + (size_t)bh * (128 * 2048) + nt * 128;
    const float* Ag0 = A + (size_t)bh * (2048 * 128);
    float*       Cg0 = C + (size_t)bh * (2048 * 2048) + nt * 128;

    const int t = threadIdx.x;

    // ---- stage B tile: 128(k) x 128(n) fp32, in-register 4x4 transpose
    //      -> bf16 LDS Bt[n][k], swizzled ----
#pragma unroll
    for (int s = 0; s < 4; ++s) {
        const int k0 = s * 32 + ((t >> 5) << 2);
        const int n0 = (t & 31) << 2;
        const float4 r0 = *(const float4*)(Bg + (size_t)(k0 + 0) * 2048 + n0);
        const float4 r1 = *(const float4*)(Bg + (size_t)(k0 + 1) * 2048 + n0);
        const float4 r2 = *(const float4*)(Bg + (size_t)(k0 + 2) * 2048 + n0);
        const float4 r3 = *(const float4*)(Bg + (size_t)(k0 + 3) * 2048 + n0);
        const float c0[4] = {r0.x, r0.y, r0.z, r0.w};
        const float c1[4] = {r1.x, r1.y, r1.z, r1.w};
        const float c2[4] = {r2.x, r2.y, r2.z, r2.w};
        const float c3[4] = {r3.x, r3.y, r3.z, r3.w};
#pragma unroll
        for (int j = 0; j < 4; ++j) {
            uint2 w;
            w.x = (unsigned int)f2bf(c0[j]) | ((unsigned int)f2bf(c1[j]) << 16);
            w.y = (unsigned int)f2bf(c2[j]) | ((unsigned int)f2bf(c3[j]) << 16);
            *(uint2*)(&lds[swz(n0 + j, k0)]) = w;
        }
    }

    __syncthreads();

    // ---- persistent mt-loop: wave w owns rows [w*32, w*32+32) of each tile
    const int l  = t & 63;
    const int w  = t >> 6;
    const int wm = w * 32;
    const int lr = l & 15;          // fragment lane row
    const int lg = l >> 4;          // k-group (0..3)

    f32x4  raw[2][4][2];            // prefetched fp32 A fragments [mi][kk][half]
    bf16x8 abf[2][4];               // converted bf16 A fragments [mi][kk]

    // prefetch mt = 0
#pragma unroll
    for (int mi = 0; mi < 2; ++mi) {
        const float* p = Ag0 + (size_t)(wm + mi * 16 + lr) * 128 + lg * 8;
#pragma unroll
        for (int kk = 0; kk < 4; ++kk) {
            raw[mi][kk][0] = *(const f32x4*)(p + kk * 32);
            raw[mi][kk][1] = *(const f32x4*)(p + kk * 32 + 4);
        }
    }

#pragma unroll 1
    for (int mt = 0; mt < 16; ++mt) {
        // convert prefetched raw -> bf16 fragments (frees raw for next prefetch)
#pragma unroll
        for (int mi = 0; mi < 2; ++mi)
#pragma unroll
            for (int kk = 0; kk < 4; ++kk) {
                bf16x8 v;
#pragma unroll
                for (int j = 0; j < 4; ++j) {
                    v[j]     = (short)f2bf(raw[mi][kk][0][j]);
                    v[4 + j] = (short)f2bf(raw[mi][kk][1][j]);
                }
                abf[mi][kk] = v;
            }

        // issue next tile's A loads BEFORE this tile's stores (older in vmcnt
        // FIFO -> never wait behind store drain)
        if (mt < 15) {
#pragma unroll
            for (int mi = 0; mi < 2; ++mi) {
                const float* p = Ag0 + (size_t)((mt + 1) * 128 + wm + mi * 16 + lr) * 128 + lg * 8;
#pragma unroll
                for (int kk = 0; kk < 4; ++kk) {
                    raw[mi][kk][0] = *(const f32x4*)(p + kk * 32);
                    raw[mi][kk][1] = *(const f32x4*)(p + kk * 32 + 4);
                }
            }
        }

        f32x4 acc[2][8] = {};
#pragma unroll
        for (int kk = 0; kk < 4; ++kk) {
            const int kbase = kk * 32 + lg * 8;
#pragma unroll
            for (int ni = 0; ni < 8; ++ni) {
                const bf16x8 b = *(const bf16x8*)(&lds[swz(ni * 16 + lr, kbase)]);
                // swapped operands: D rows = n, cols = m  ->  lane holds
                // C[m = lr][n = ni*16 + lg*4 + j], contiguous in C rows
                acc[0][ni] = __builtin_amdgcn_mfma_f32_16x16x32_bf16(b, abf[0][kk], acc[0][ni], 0, 0, 0);
                acc[1][ni] = __builtin_amdgcn_mfma_f32_16x16x32_bf16(b, abf[1][kk], acc[1][ni], 0, 0, 0);
            }
        }

        // dense dwordx4 stores: 1 KB contiguous per wave-instruction
        float* Cr = Cg0 + (size_t)(mt * 128) * 2048;
#pragma unroll
        for (int mi = 0; mi < 2; ++mi) {
            float* rowp = Cr + (size_t)(wm + mi * 16 + lr) * 2048 + lg * 4;
#pragma unroll
            for (int ni = 0; ni < 8; ++ni) {
                __builtin_nontemporal_store(acc[mi][ni], (f32x4*)(rowp + ni * 16));
            }
        }
    }
}

extern "C" void kernel_launch(void* const* d_in, const int* in_sizes, int n_in,
                              void* d_out, int out_size, void* d_ws, size_t ws_size,
                              hipStream_t stream) {
    const float* x1 = (const float*)d_in[0];  // (2,16,2048,128)
    const float* x2 = (const float*)d_in[1];  // (2,16,128,2048)
    float* out = (float*)d_out;               // (2,16,2048,2048)
    gemm_persist<<<dim3(512), dim3(256), 0, stream>>>(x1, x2, out);
}